// Round 1
// baseline (263.394 us; speedup 1.0000x reference)
//
#include <hip/hip_runtime.h>
#include <hip/hip_bf16.h>

// One block per row. Per-element coefficient form of the masked trapezoid:
//   coeff(k) = 0.5 * ( (x[k]-x[k-1]) * [1 <= k <= idx]  +  (x[k+1]-x[k]) * [k < idx] )
//   row_sum  = sum_k coeff(k) * (y_pred[k] - y_true[k])
// Elements with k > idx are never loaded (average halves HBM traffic).
__global__ __launch_bounds__(256) void strain_loss_kernel(
    const float* __restrict__ y_pred,
    const float* __restrict__ y_true,
    const float* __restrict__ x,
    const int*   __restrict__ fidx,
    float* __restrict__ out,
    int n, float inv_b)
{
    const int row = blockIdx.x;
    const int tid = threadIdx.x;

    int idx = fidx[row];
    idx = idx < 0 ? 0 : (idx > n - 1 ? n - 1 : idx);

    const float* p = y_pred + (long long)row * n;
    const float* t = y_true + (long long)row * n;

    float acc = 0.0f;
    // float4 strides of 256 threads; only vectors whose first element is <= idx.
    for (int k0 = tid * 4; k0 <= idx; k0 += 256 * 4) {
        float4 pv = *(const float4*)(p + k0);
        float4 tv = *(const float4*)(t + k0);
        float4 xv = *(const float4*)(x + k0);
        float xm = (k0 >= 1)     ? x[k0 - 1] : xv.x;   // unused value when k0==0
        float xp = (k0 + 4 < n)  ? x[k0 + 4] : xv.w;   // unused value when masked
        float xs[6] = {xm, xv.x, xv.y, xv.z, xv.w, xp};
        float dv[4] = {pv.x - tv.x, pv.y - tv.y, pv.z - tv.z, pv.w - tv.w};
        #pragma unroll
        for (int e = 0; e < 4; ++e) {
            int k = k0 + e;
            float left  = (k >= 1 && k <= idx) ? (xs[e + 1] - xs[e])     : 0.0f;
            float right = (k < idx)            ? (xs[e + 2] - xs[e + 1]) : 0.0f;
            acc += 0.5f * (left + right) * dv[e];
        }
    }

    // Wave (64-lane) shuffle reduction, then cross-wave via LDS.
    #pragma unroll
    for (int off = 32; off > 0; off >>= 1)
        acc += __shfl_down(acc, off, 64);

    __shared__ float wave_sums[4];
    const int wave = tid >> 6;
    if ((tid & 63) == 0) wave_sums[wave] = acc;
    __syncthreads();

    if (tid == 0) {
        float s = wave_sums[0] + wave_sums[1] + wave_sums[2] + wave_sums[3];
        atomicAdd(out, s * s * inv_b);   // mean of squared errors
    }
}

extern "C" void kernel_launch(void* const* d_in, const int* in_sizes, int n_in,
                              void* d_out, int out_size, void* d_ws, size_t ws_size,
                              hipStream_t stream) {
    const float* y_pred = (const float*)d_in[0];
    const float* y_true = (const float*)d_in[1];
    const float* x      = (const float*)d_in[2];
    const int*   fidx   = (const int*)d_in[3];
    float* out = (float*)d_out;

    const int n = in_sizes[2];   // 8192
    const int b = in_sizes[3];   // 4096

    // d_out is poisoned 0xAA before every timed launch — zero it on-stream.
    hipMemsetAsync(d_out, 0, sizeof(float), stream);

    strain_loss_kernel<<<dim3(b), dim3(256), 0, stream>>>(
        y_pred, y_true, x, fidx, out, n, 1.0f / (float)b);
}